// Round 12
// baseline (105.861 us; speedup 1.0000x reference)
//
#include <hip/hip_runtime.h>
#include <hip/hip_bf16.h>

#define A_  512
#define D_  512
#define H_  8
#define HD_ 64
#define TD_ 1536   // 3*D
#define RH_ 512    // REL_HID

typedef __attribute__((ext_vector_type(8))) short short8v;
typedef __attribute__((ext_vector_type(4))) float f32x4;
typedef __attribute__((ext_vector_type(4))) unsigned int u32x4;
union V8 { u32x4 u; short8v s; };

__device__ __forceinline__ unsigned short f2bf(float f) {
    unsigned int u = __float_as_uint(f);
    u += 0x7FFFu + ((u >> 16) & 1u);
    return (unsigned short)(u >> 16);
}
// pack 2 f32 -> 2 bf16 in one v_cvt_pk_bf16_f32 (no builtin on gfx950)
__device__ __forceinline__ unsigned pk2(float a, float b) {
    unsigned r;
    asm("v_cvt_pk_bf16_f32 %0, %1, %2" : "=v"(r) : "v"(a), "v"(b));
    return r;
}
// relu + pack
__device__ __forceinline__ unsigned pk2r(float a, float b) {
    return pk2(fmaxf(a, 0.f), fmaxf(b, 0.f));
}

// ---------------------------------------------------------------------------
// Transpose + cvt body: fp32 [R][C] -> bf16 [C][R], 64x64 tile.
// ---------------------------------------------------------------------------
__device__ __forceinline__ void wt_body(float (*ts)[65],
                                        const float* __restrict__ in,
                                        ushort* __restrict__ out,
                                        int R, int C, int bx, int by) {
    const int tid = threadIdx.x;
    const int r0 = by * 64, c0 = bx * 64;
    const int r = tid >> 2, cb = (tid & 3) * 16;
    #pragma unroll
    for (int u = 0; u < 4; ++u) {
        const float4 v = *(const float4*)&in[(size_t)(r0 + r) * C + c0 + cb + u*4];
        ts[r][cb + u*4 + 0] = v.x;
        ts[r][cb + u*4 + 1] = v.y;
        ts[r][cb + u*4 + 2] = v.z;
        ts[r][cb + u*4 + 3] = v.w;
    }
    __syncthreads();
    const int oc = tid & 63;
    const int rb = (tid >> 6) * 16;
    unsigned pk[8];
    #pragma unroll
    for (int i = 0; i < 8; ++i) {
        pk[i] = pk2(ts[rb + i*2][oc], ts[rb + i*2 + 1][oc]);
    }
    uint4* dst = (uint4*)&out[(size_t)(c0 + oc) * R + r0 + rb];
    dst[0] = make_uint4(pk[0], pk[1], pk[2], pk[3]);
    dst[1] = make_uint4(pk[4], pk[5], pk[6], pk[7]);
}

// ---------------------------------------------------------------------------
// prep2: [0,256) x->bf16 ; 256 mask bias ; [257,449) qkv_w^T ;
//        [449,641) ff_w1^T ; [641,833) ff_w2^T.
// ---------------------------------------------------------------------------
__global__ __launch_bounds__(256) void prep2_kernel(const float* __restrict__ x,
                                                    const void* __restrict__ mraw,
                                                    const float* __restrict__ qkv_w,
                                                    const float* __restrict__ ff_w1,
                                                    const float* __restrict__ ff_w2,
                                                    ushort* __restrict__ xb,
                                                    float* __restrict__ maskf,
                                                    ushort* __restrict__ wtb1,
                                                    ushort* __restrict__ wtb2,
                                                    ushort* __restrict__ wtb3) {
    __shared__ __align__(16) float ts[64][65];
    const int tid = threadIdx.x;
    const int bid = blockIdx.x;
    if (bid < 256) {
        const int i = (bid * 256 + tid) * 8;
        const float4 a = *(const float4*)&x[i];
        const float4 b = *(const float4*)&x[i + 4];
        uint4 o;
        o.x = pk2(a.x, a.y);
        o.y = pk2(a.z, a.w);
        o.z = pk2(b.x, b.y);
        o.w = pk2(b.z, b.w);
        *(uint4*)&xb[i] = o;
    } else if (bid == 256) {
        int* anyOdd = (int*)ts;
        if (tid == 0) *anyOdd = 0;
        __syncthreads();
        const unsigned char* mb = (const unsigned char*)mraw;
        int local = 0;
        #pragma unroll
        for (int u = 0; u < 4; ++u) {
            const int i = tid * 4 + u;
            if ((i & 3) != 0 && mb[i] != 0) local = 1;
        }
        if (local) atomicOr(anyOdd, 1);
        __syncthreads();
        const bool isByte = (*anyOdd != 0);
        #pragma unroll
        for (int u = 0; u < 4; ++u) {
            const int i = tid * 4 + u;
            int set = isByte ? (mb[i] != 0) : (((const int*)mraw)[i] != 0);
            maskf[i] = set ? -1e9f : 0.0f;
        }
    } else if (bid < 449) {
        const int i = bid - 257;
        wt_body(ts, qkv_w, wtb1, 512, 1536, i % 24, i / 24);
    } else if (bid < 641) {
        const int i = bid - 449;
        wt_body(ts, ff_w1, wtb2, 512, 1536, i % 24, i / 24);
    } else {
        const int i = bid - 641;
        wt_body(ts, ff_w2, wtb3, 1536, 512, i % 8, i / 8);
    }
}

// ---------------------------------------------------------------------------
// bf16 MFMA GEMM body (64x64 tile, BK=64, 4 waves, slot-XOR swizzle).
// ---------------------------------------------------------------------------
template<int RELU, int OBF16, int SCALEQ>
__device__ __forceinline__ void mgemm_body(ushort* As, ushort* Bs,
                                           const ushort* __restrict__ A,
                                           const ushort* __restrict__ BT,
                                           const float* __restrict__ bias,
                                           void* __restrict__ Cv,
                                           int N, int K, int bm, int bn) {
    const int tid = threadIdx.x;
    const int lane = tid & 63, wave = tid >> 6;
    const int wm = (wave >> 1) * 32, wn = (wave & 1) * 32;
    f32x4 acc[2][2];
    #pragma unroll
    for (int i = 0; i < 2; ++i)
        #pragma unroll
        for (int j = 0; j < 2; ++j) acc[i][j] = (f32x4){0.f, 0.f, 0.f, 0.f};

    const int s0  = tid * 2;
    const int rs  = s0 >> 3;
    const int sl0 = s0 & 7;
    for (int k0 = 0; k0 < K; k0 += 64) {
        #pragma unroll
        for (int u = 0; u < 2; ++u) {
            const int sl = sl0 + u;
            const uint4 va = *(const uint4*)&A[(size_t)(bm + rs) * K + k0 + sl*8];
            *(uint4*)((char*)As + rs*128 + ((sl ^ (rs & 7)) << 4)) = va;
            const uint4 vb = *(const uint4*)&BT[(size_t)(bn + rs) * K + k0 + sl*8];
            *(uint4*)((char*)Bs + rs*128 + ((sl ^ (rs & 7)) << 4)) = vb;
        }
        __syncthreads();
        #pragma unroll
        for (int kk = 0; kk < 2; ++kk) {
            short8v af[2], bfv[2];
            #pragma unroll
            for (int mf = 0; mf < 2; ++mf) {
                const int row = wm + mf*16 + (lane & 15);
                const int slot = (kk*4 + (lane >> 4)) ^ (row & 7);
                af[mf] = *(const short8v*)((const char*)As + row*128 + (slot << 4));
            }
            #pragma unroll
            for (int nf = 0; nf < 2; ++nf) {
                const int row = wn + nf*16 + (lane & 15);
                const int slot = (kk*4 + (lane >> 4)) ^ (row & 7);
                bfv[nf] = *(const short8v*)((const char*)Bs + row*128 + (slot << 4));
            }
            #pragma unroll
            for (int mf = 0; mf < 2; ++mf)
                #pragma unroll
                for (int nf = 0; nf < 2; ++nf)
                    acc[mf][nf] = __builtin_amdgcn_mfma_f32_16x16x32_bf16(af[mf], bfv[nf], acc[mf][nf], 0, 0, 0);
        }
        __syncthreads();
    }
    #pragma unroll
    for (int nf = 0; nf < 2; ++nf) {
        const int col = bn + wn + nf*16 + (lane & 15);
        const float bv = bias[col];
        const float qs = (SCALEQ && col < D_) ? 0.125f : 1.0f;
        #pragma unroll
        for (int mf = 0; mf < 2; ++mf) {
            #pragma unroll
            for (int r = 0; r < 4; ++r) {
                const int row = bm + wm + mf*16 + (lane >> 4)*4 + r;
                float v = acc[mf][nf][r] + bv;
                if (RELU) v = fmaxf(v, 0.f);
                if (SCALEQ) v *= qs;
                if (OBF16) ((ushort*)Cv)[(size_t)row * N + col] = f2bf(v);
                else       ((float*)Cv)[(size_t)row * N + col] = v;
            }
        }
    }
}

template<int RELU, int OBF16, int SCALEQ>
__global__ __launch_bounds__(256) void mgemm_kernel(const ushort* __restrict__ A,
                                                    const ushort* __restrict__ BT,
                                                    const float* __restrict__ bias,
                                                    void* __restrict__ Cv,
                                                    int M, int N, int K) {
    __shared__ __align__(16) ushort As[64 * 64];
    __shared__ __align__(16) ushort Bs[64 * 64];
    mgemm_body<RELU, OBF16, SCALEQ>(As, Bs, A, BT, bias, Cv, N, K,
                                    blockIdx.y * 64, blockIdx.x * 64);
}

// ---------------------------------------------------------------------------
// relmlp body: both layers MFMA, in-register handoff (w2 k-permuted).
// This round: 8 pair-tiles (128 pairs) per wave -> per-chunk weight loads
// amortize 8-ways, preamble cost halves (1024 blocks).
// ---------------------------------------------------------------------------
__device__ __forceinline__ void relmlp_body(ushort* w1t, ushort* w2t,
                                            const float* __restrict__ rel,
                                            const float* __restrict__ w1,
                                            const float* __restrict__ b1,
                                            const float* __restrict__ w2,
                                            const float* __restrict__ maskf,
                                            ushort* __restrict__ relbM,
                                            int bid) {
    const int tid = threadIdx.x;
    #pragma unroll
    for (int u = 0; u < 2; ++u) {
        const int n = tid + u*256;
        uint4 o;
        o.x = (unsigned)f2bf(w1[n])        | ((unsigned)f2bf(w1[512 + n])  << 16);
        o.y = (unsigned)f2bf(w1[1024 + n]) | ((unsigned)f2bf(w1[1536 + n]) << 16);
        o.z = (unsigned)f2bf(b1[n]);
        o.w = 0;
        *(uint4*)&w1t[n * 8] = o;
        const int ch = n >> 5, w = n & 31, t = w >> 4, i = w & 15;
        const int s = ((i >> 2) << 3) + (t << 2) + (i & 3);
        const int kpos = ch * 32 + s;
        const float4 wlo = *(const float4*)&w2[n*8];
        const float4 whi = *(const float4*)&w2[n*8 + 4];
        const float wvv[8] = {wlo.x, wlo.y, wlo.z, wlo.w, whi.x, whi.y, whi.z, whi.w};
        #pragma unroll
        for (int h = 0; h < 8; ++h) {
            *(ushort*)((char*)w2t + h*1024 + (((kpos >> 3) ^ h) << 4) + (kpos & 7)*2) = f2bf(wvv[h]);
        }
    }
    __syncthreads();

    const int lane = tid & 63, wvid = tid >> 6;
    const int g = lane >> 4, lr = lane & 15;
    const f32x4 z4 = {0.f, 0.f, 0.f, 0.f};
    const int pbase = bid * 512 + wvid * 128;   // 128 pairs per wave

    short8v rf[8];
    #pragma unroll
    for (int pt = 0; pt < 8; ++pt) {
        short8v r8 = {0,0,0,0,0,0,0,0};
        if (g == 0) {
            const float4 ra = *(const float4*)&rel[(size_t)(pbase + pt*16 + lr) * 4];
            r8[0] = (short)f2bf(ra.x); r8[1] = (short)f2bf(ra.y);
            r8[2] = (short)f2bf(ra.z); r8[3] = (short)f2bf(ra.w);
            r8[4] = (short)0x3F80;
        }
        rf[pt] = r8;
    }
    f32x4 acc[8];
    #pragma unroll
    for (int pt = 0; pt < 8; ++pt) acc[pt] = z4;

    #pragma unroll 2
    for (int ch = 0; ch < 16; ++ch) {
        const short8v a2  = *(const short8v*)((const char*)w2t + (lr & 7)*1024 + (((ch*4 + g) ^ (lr & 7)) << 4));
        const short8v af0 = *(const short8v*)&w1t[(ch*32 + lr) * 8];
        const short8v af1 = *(const short8v*)&w1t[(ch*32 + 16 + lr) * 8];
        #pragma unroll
        for (int pt = 0; pt < 8; ++pt) {
            const f32x4 c0 = __builtin_amdgcn_mfma_f32_16x16x32_bf16(af0, rf[pt], z4, 0, 0, 0);
            const f32x4 c1 = __builtin_amdgcn_mfma_f32_16x16x32_bf16(af1, rf[pt], z4, 0, 0, 0);
            V8 bfrag;
            bfrag.u.x = pk2r(c0[0], c0[1]); bfrag.u.y = pk2r(c0[2], c0[3]);
            bfrag.u.z = pk2r(c1[0], c1[1]); bfrag.u.w = pk2r(c1[2], c1[3]);
            acc[pt] = __builtin_amdgcn_mfma_f32_16x16x32_bf16(a2, bfrag.s, acc[pt], 0, 0, 0);
        }
    }
    if (g < 2) {
        #pragma unroll
        for (int pt = 0; pt < 8; ++pt) {
            const int pair = pbase + pt*16 + lr;
            const int bb_  = pair >> 18;
            const int ij   = pair & 262143;
            const float mv = maskf[bb_ * A_ + (pair & 511)];
            ushort* dst = relbM + (((size_t)(bb_ * 8)) << 18) + ij;
            #pragma unroll
            for (int r = 0; r < 4; ++r) {
                const int h = g*4 + r;
                dst[(size_t)h << 18] = f2bf(16.0f / (1.0f + __expf(-acc[pt][r])) + mv);
            }
        }
    }
}

// ---------------------------------------------------------------------------
// fused: blocks [0,384) qkv GEMM (Q pre-scaled, bf16 out); [384,1408) relmlp.
// ---------------------------------------------------------------------------
__global__ __launch_bounds__(256) void fused_qr_kernel(const ushort* __restrict__ xb,
                                                       const ushort* __restrict__ wtb1,
                                                       const float* __restrict__ qkv_b,
                                                       ushort* __restrict__ qkvb,
                                                       const float* __restrict__ rel,
                                                       const float* __restrict__ w1,
                                                       const float* __restrict__ b1,
                                                       const float* __restrict__ w2,
                                                       const float* __restrict__ maskf,
                                                       ushort* __restrict__ relbM) {
    __shared__ __align__(16) char smem[16384];
    const int bid = blockIdx.x;
    if (bid < 384) {
        mgemm_body<0, 1, 1>((ushort*)smem, (ushort*)(smem + 8192),
                            xb, wtb1, qkv_b, qkvb, 1536, 512,
                            (bid / 24) * 64, (bid % 24) * 64);
    } else {
        relmlp_body((ushort*)smem, (ushort*)(smem + 8192),
                    rel, w1, b1, w2, maskf, relbM, bid - 384);
    }
}

// ---------------------------------------------------------------------------
// VT[bh][d][j] bf16 <- V rows in qkvb. 64x64 tiles.
// ---------------------------------------------------------------------------
__global__ __launch_bounds__(256) void vt_kernel(const ushort* __restrict__ qkvb,
                                                 ushort* __restrict__ VT) {
    const int bh = blockIdx.y, jt = blockIdx.x;
    const int b = bh >> 3, h = bh & 7;
    __shared__ ushort ts[64][72];
    const int tid = threadIdx.x;
    const int r = tid >> 2, c16 = (tid & 3) * 16;
    const ushort* src = qkvb + (size_t)(b*A_ + jt*64 + r) * TD_ + 2*D_ + h*HD_ + c16;
    *(uint4*)&ts[r][c16]     = *(const uint4*)&src[0];
    *(uint4*)&ts[r][c16 + 8] = *(const uint4*)&src[8];
    __syncthreads();
    const int d = tid >> 2, jb = (tid & 3) * 16;
    unsigned pk[8];
    #pragma unroll
    for (int i = 0; i < 8; ++i)
        pk[i] = (unsigned)ts[jb + i*2][d] | ((unsigned)ts[jb + i*2 + 1][d] << 16);
    uint4* dst = (uint4*)&VT[(size_t)(bh*64 + d) * A_ + jt*64 + jb];
    dst[0] = make_uint4(pk[0], pk[1], pk[2], pk[3]);
    dst[1] = make_uint4(pk[4], pk[5], pk[6], pk[7]);
}

// ---------------------------------------------------------------------------
// Fused attention: one wave per (bh, 16-row i-tile). Swapped QK^T; softmax
// in-register; P via swizzled LDS; V-frags straight from VT. S,P never global.
// ---------------------------------------------------------------------------
__global__ __launch_bounds__(64) void attn_kernel(const ushort* __restrict__ qkvb,
                                                  const ushort* __restrict__ relbM,
                                                  const ushort* __restrict__ vtb,
                                                  float* __restrict__ outb) {
    const int blk = blockIdx.x;
    const int bh = blk >> 5, it = blk & 31;
    const int b = bh >> 3, h = bh & 7;
    const int i0 = it * 16;
    const int lane = threadIdx.x;
    const int g = lane >> 4, lr = lane & 15;
    __shared__ __align__(16) ushort Pl[16 * 512];

    const ushort* Qrow = qkvb + (size_t)(b*A_ + i0 + lr) * TD_ + h*HD_;
    const short8v qf0 = *(const short8v*)&Qrow[g*8];
    const short8v qf1 = *(const short8v*)&Qrow[32 + g*8];

    const ushort* Kbase = qkvb + (size_t)(b*A_) * TD_ + D_ + h*HD_;
    f32x4 s[32];
    #pragma unroll
    for (int jt = 0; jt < 32; ++jt) {
        const ushort* Krow = Kbase + (size_t)(jt*16 + lr) * TD_;
        const short8v a0 = *(const short8v*)&Krow[g*8];
        const short8v a1 = *(const short8v*)&Krow[32 + g*8];
        f32x4 c = {0.f, 0.f, 0.f, 0.f};
        c = __builtin_amdgcn_mfma_f32_16x16x32_bf16(a0, qf0, c, 0, 0, 0);
        c = __builtin_amdgcn_mfma_f32_16x16x32_bf16(a1, qf1, c, 0, 0, 0);
        s[jt] = c;
    }
    const ushort* rb = relbM + ((size_t)bh << 18) + (size_t)(i0 + lr) * A_;
    #pragma unroll
    for (int jt = 0; jt < 32; ++jt) {
        const uint2 m2 = *(const uint2*)&rb[jt*16 + g*4];
        s[jt][0] += __uint_as_float(m2.x << 16);
        s[jt][1] += __uint_as_float(m2.x & 0xFFFF0000u);
        s[jt][2] += __uint_as_float(m2.y << 16);
        s[jt][3] += __uint_as_float(m2.y & 0xFFFF0000u);
    }
    float mx = -3.0e38f;
    #pragma unroll
    for (int jt = 0; jt < 32; ++jt)
        mx = fmaxf(mx, fmaxf(fmaxf(s[jt][0], s[jt][1]), fmaxf(s[jt][2], s[jt][3])));
    mx = fmaxf(mx, __shfl_xor(mx, 16));
    mx = fmaxf(mx, __shfl_xor(mx, 32));
    float sum = 0.f;
    #pragma unroll
    for (int jt = 0; jt < 32; ++jt) {
        #pragma unroll
        for (int r = 0; r < 4; ++r) {
            const float e = __expf(s[jt][r] - mx);
            s[jt][r] = e;
            sum += e;
        }
    }
    sum += __shfl_xor(sum, 16);
    sum += __shfl_xor(sum, 32);
    const float inv = 1.0f / sum;
    char* Plc = (char*)Pl;
    #pragma unroll
    for (int jt = 0; jt < 32; ++jt) {
        uint2 w;
        w.x = pk2(s[jt][0] * inv, s[jt][1] * inv);
        w.y = pk2(s[jt][2] * inv, s[jt][3] * inv);
        const int j0 = jt*16 + g*4;
        *(uint2*)(Plc + lr*1024 + (((j0 >> 3) ^ (lr & 7)) << 4) + (j0 & 7)*2) = w;
    }
    __syncthreads();
    f32x4 o[4];
    #pragma unroll
    for (int dt = 0; dt < 4; ++dt) o[dt] = (f32x4){0.f, 0.f, 0.f, 0.f};
    const ushort* Vb = vtb + (size_t)bh * 64 * A_;
    #pragma unroll
    for (int c = 0; c < 16; ++c) {
        const short8v pa = *(const short8v*)(Plc + lr*1024 + (((c*4 + g) ^ (lr & 7)) << 4));
        #pragma unroll
        for (int dt = 0; dt < 4; ++dt) {
            const short8v vf = *(const short8v*)&Vb[(size_t)(dt*16 + lr) * A_ + c*32 + g*8];
            o[dt] = __builtin_amdgcn_mfma_f32_16x16x32_bf16(pa, vf, o[dt], 0, 0, 0);
        }
    }
    float* Ob = outb + (size_t)(b*A_ + i0) * D_ + h*HD_;
    #pragma unroll
    for (int dt = 0; dt < 4; ++dt)
        #pragma unroll
        for (int r = 0; r < 4; ++r)
            Ob[(size_t)(g*4 + r) * D_ + dt*16 + lr] = o[dt][r];
}

// ---------------------------------------------------------------------------
// Fused residual + LayerNorm (512). Optional bf16 copy of the output.
// ---------------------------------------------------------------------------
template<int BF16OUT>
__global__ __launch_bounds__(256) void ln_kernel(const float* __restrict__ a,
                                                 const float* __restrict__ r,
                                                 const float* __restrict__ g,
                                                 const float* __restrict__ bb,
                                                 float* __restrict__ out,
                                                 ushort* __restrict__ outb) {
    const int row = blockIdx.x;
    const int tid = threadIdx.x;
    const size_t base = (size_t)row * D_ + tid * 2;
    const float2 a2 = *reinterpret_cast<const float2*>(&a[base]);
    const float2 r2 = *reinterpret_cast<const float2*>(&r[base]);
    const float e0 = a2.x + r2.x, e1 = a2.y + r2.y;
    float s = e0 + e1;
    float q = e0*e0 + e1*e1;
    #pragma unroll
    for (int o = 32; o > 0; o >>= 1) { s += __shfl_down(s, o); q += __shfl_down(q, o); }
    __shared__ float rs[4], rq[4];
    if ((tid & 63) == 0) { rs[tid >> 6] = s; rq[tid >> 6] = q; }
    __syncthreads();
    const float S = rs[0]+rs[1]+rs[2]+rs[3];
    const float Q = rq[0]+rq[1]+rq[2]+rq[3];
    const float mean = S * (1.0f/512.0f);
    const float var  = Q * (1.0f/512.0f) - mean*mean;
    const float rstd = rsqrtf(var + 1e-5f);
    const int c = tid*2;
    float2 ov;
    ov.x = (e0 - mean)*rstd*g[c]   + bb[c];
    ov.y = (e1 - mean)*rstd*g[c+1] + bb[c+1];
    *reinterpret_cast<float2*>(&out[base]) = ov;
    if (BF16OUT) {
        *(unsigned*)&outb[base] = pk2(ov.x, ov.y);
    }
}

// ---------------------------------------------------------------------------
extern "C" void kernel_launch(void* const* d_in, const int* in_sizes, int n_in,
                              void* d_out, int out_size, void* d_ws, size_t ws_size,
                              hipStream_t stream) {
    const float* x        = (const float*)d_in[0];
    const void*  mask     = d_in[1];
    const float* relation = (const float*)d_in[2];
    const float* qkv_w    = (const float*)d_in[3];
    const float* qkv_b    = (const float*)d_in[4];
    const float* rel_w1   = (const float*)d_in[5];
    const float* rel_b1   = (const float*)d_in[6];
    const float* rel_w2   = (const float*)d_in[7];
    const float* ff_w1    = (const float*)d_in[8];
    const float* ff_b1    = (const float*)d_in[9];
    const float* ff_w2    = (const float*)d_in[10];
    const float* ff_b2    = (const float*)d_in[11];
    const float* ln1_g    = (const float*)d_in[12];
    const float* ln1_b    = (const float*)d_in[13];
    const float* ln2_g    = (const float*)d_in[14];
    const float* ln2_b    = (const float*)d_in[15];
    float* out = (float*)d_out;

    float* ws     = (float*)d_ws;
    ushort* relbM = (ushort*)ws;                   // 4,194,304 ush (bf16, +mask)
    float*  maskf = (float*)(relbM + 4194304);     // 1,024 f
    float*  attnb = maskf + 1024;                  // 524,288 f
    float*  x1    = attnb + 524288;                // 524,288 f
    ushort* wtb1  = (ushort*)(x1 + 524288);        // 786,432 ush (qkv_w^T)
    ushort* wtb2  = wtb1 + 786432;                 // 786,432 ush (ff_w1^T)
    ushort* wtb3  = wtb2 + 786432;                 // 786,432 ush (ff_w2^T)
    ushort* xb    = wtb3 + 786432;                 // 524,288 ush
    ushort* ffhb  = xb  + 524288;                  // 1,572,864 ush
    ushort* qkvb  = ffhb + 1572864;                // 1,572,864 ush (bf16 qkv, Q pre-scaled)
    ushort* vtb   = qkvb + 1572864;                // 524,288 ush (V^T)
    float*  ff2o  = (float*)qkvb;                  // reuse: qkvb dead after attn
    ushort* x1b   = xb;                            // reuse: xb dead after fused_qr

    prep2_kernel<<<833, 256, 0, stream>>>(x, mask, qkv_w, ff_w1, ff_w2,
                                          xb, maskf, wtb1, wtb2, wtb3);
    // qkv GEMM (blocks 0..383) concurrent with relmlp (blocks 384..1407)
    fused_qr_kernel<<<1408, 256, 0, stream>>>(xb, wtb1, qkv_b, qkvb,
                                              relation, rel_w1, rel_b1, rel_w2,
                                              maskf, relbM);
    vt_kernel<<<dim3(8, 16), 256, 0, stream>>>(qkvb, vtb);
    attn_kernel<<<512, 64, 0, stream>>>(qkvb, relbM, vtb, attnb);
    ln_kernel<1><<<1024, 256, 0, stream>>>(attnb, x, ln1_g, ln1_b, x1, x1b);
    mgemm_kernel<1,1,0><<<dim3(24, 16), 256, 0, stream>>>(x1b, wtb2, ff_b1, ffhb, 1024, 1536, 512);
    mgemm_kernel<0,0,0><<<dim3(8, 16), 256, 0, stream>>>(ffhb, wtb3, ff_b2, ff2o, 1024, 512, 1536);
    ln_kernel<0><<<1024, 256, 0, stream>>>(ff2o, x1, ln2_g, ln2_b, out, nullptr);
}

// Round 13
// 103.772 us; speedup vs baseline: 1.0201x; 1.0201x over previous
//
#include <hip/hip_runtime.h>
#include <hip/hip_bf16.h>

#define A_  512
#define D_  512
#define H_  8
#define HD_ 64
#define TD_ 1536   // 3*D
#define RH_ 512    // REL_HID

typedef __attribute__((ext_vector_type(8))) short short8v;
typedef __attribute__((ext_vector_type(4))) float f32x4;
typedef __attribute__((ext_vector_type(4))) unsigned int u32x4;
union V8 { u32x4 u; short8v s; };

__device__ __forceinline__ unsigned short f2bf(float f) {
    unsigned int u = __float_as_uint(f);
    u += 0x7FFFu + ((u >> 16) & 1u);
    return (unsigned short)(u >> 16);
}
// pack 2 f32 -> 2 bf16 in one v_cvt_pk_bf16_f32 (no builtin on gfx950)
__device__ __forceinline__ unsigned pk2(float a, float b) {
    unsigned r;
    asm("v_cvt_pk_bf16_f32 %0, %1, %2" : "=v"(r) : "v"(a), "v"(b));
    return r;
}
// relu + pack
__device__ __forceinline__ unsigned pk2r(float a, float b) {
    return pk2(fmaxf(a, 0.f), fmaxf(b, 0.f));
}

// ---------------------------------------------------------------------------
// Transpose + cvt body: fp32 [R][C] -> bf16 [C][R], 64x64 tile.
// ---------------------------------------------------------------------------
__device__ __forceinline__ void wt_body(float (*ts)[65],
                                        const float* __restrict__ in,
                                        ushort* __restrict__ out,
                                        int R, int C, int bx, int by) {
    const int tid = threadIdx.x;
    const int r0 = by * 64, c0 = bx * 64;
    const int r = tid >> 2, cb = (tid & 3) * 16;
    #pragma unroll
    for (int u = 0; u < 4; ++u) {
        const float4 v = *(const float4*)&in[(size_t)(r0 + r) * C + c0 + cb + u*4];
        ts[r][cb + u*4 + 0] = v.x;
        ts[r][cb + u*4 + 1] = v.y;
        ts[r][cb + u*4 + 2] = v.z;
        ts[r][cb + u*4 + 3] = v.w;
    }
    __syncthreads();
    const int oc = tid & 63;
    const int rb = (tid >> 6) * 16;
    unsigned pk[8];
    #pragma unroll
    for (int i = 0; i < 8; ++i) {
        pk[i] = pk2(ts[rb + i*2][oc], ts[rb + i*2 + 1][oc]);
    }
    uint4* dst = (uint4*)&out[(size_t)(c0 + oc) * R + r0 + rb];
    dst[0] = make_uint4(pk[0], pk[1], pk[2], pk[3]);
    dst[1] = make_uint4(pk[4], pk[5], pk[6], pk[7]);
}

// ---------------------------------------------------------------------------
// prep2: [0,256) x->bf16 ; 256 mask bias ; [257,449) qkv_w^T ;
//        [449,641) ff_w1^T ; [641,833) ff_w2^T.
// ---------------------------------------------------------------------------
__global__ __launch_bounds__(256) void prep2_kernel(const float* __restrict__ x,
                                                    const void* __restrict__ mraw,
                                                    const float* __restrict__ qkv_w,
                                                    const float* __restrict__ ff_w1,
                                                    const float* __restrict__ ff_w2,
                                                    ushort* __restrict__ xb,
                                                    float* __restrict__ maskf,
                                                    ushort* __restrict__ wtb1,
                                                    ushort* __restrict__ wtb2,
                                                    ushort* __restrict__ wtb3) {
    __shared__ __align__(16) float ts[64][65];
    const int tid = threadIdx.x;
    const int bid = blockIdx.x;
    if (bid < 256) {
        const int i = (bid * 256 + tid) * 8;
        const float4 a = *(const float4*)&x[i];
        const float4 b = *(const float4*)&x[i + 4];
        uint4 o;
        o.x = pk2(a.x, a.y);
        o.y = pk2(a.z, a.w);
        o.z = pk2(b.x, b.y);
        o.w = pk2(b.z, b.w);
        *(uint4*)&xb[i] = o;
    } else if (bid == 256) {
        int* anyOdd = (int*)ts;
        if (tid == 0) *anyOdd = 0;
        __syncthreads();
        const unsigned char* mb = (const unsigned char*)mraw;
        int local = 0;
        #pragma unroll
        for (int u = 0; u < 4; ++u) {
            const int i = tid * 4 + u;
            if ((i & 3) != 0 && mb[i] != 0) local = 1;
        }
        if (local) atomicOr(anyOdd, 1);
        __syncthreads();
        const bool isByte = (*anyOdd != 0);
        #pragma unroll
        for (int u = 0; u < 4; ++u) {
            const int i = tid * 4 + u;
            int set = isByte ? (mb[i] != 0) : (((const int*)mraw)[i] != 0);
            maskf[i] = set ? -1e9f : 0.0f;
        }
    } else if (bid < 449) {
        const int i = bid - 257;
        wt_body(ts, qkv_w, wtb1, 512, 1536, i % 24, i / 24);
    } else if (bid < 641) {
        const int i = bid - 449;
        wt_body(ts, ff_w1, wtb2, 512, 1536, i % 24, i / 24);
    } else {
        const int i = bid - 641;
        wt_body(ts, ff_w2, wtb3, 1536, 512, i % 8, i / 8);
    }
}

// ---------------------------------------------------------------------------
// bf16 MFMA GEMM body (64x64 tile, BK=64, 4 waves, slot-XOR swizzle).
// ---------------------------------------------------------------------------
template<int RELU, int OBF16, int SCALEQ>
__device__ __forceinline__ void mgemm_body(ushort* As, ushort* Bs,
                                           const ushort* __restrict__ A,
                                           const ushort* __restrict__ BT,
                                           const float* __restrict__ bias,
                                           void* __restrict__ Cv,
                                           int N, int K, int bm, int bn) {
    const int tid = threadIdx.x;
    const int lane = tid & 63, wave = tid >> 6;
    const int wm = (wave >> 1) * 32, wn = (wave & 1) * 32;
    f32x4 acc[2][2];
    #pragma unroll
    for (int i = 0; i < 2; ++i)
        #pragma unroll
        for (int j = 0; j < 2; ++j) acc[i][j] = (f32x4){0.f, 0.f, 0.f, 0.f};

    const int s0  = tid * 2;
    const int rs  = s0 >> 3;
    const int sl0 = s0 & 7;
    for (int k0 = 0; k0 < K; k0 += 64) {
        #pragma unroll
        for (int u = 0; u < 2; ++u) {
            const int sl = sl0 + u;
            const uint4 va = *(const uint4*)&A[(size_t)(bm + rs) * K + k0 + sl*8];
            *(uint4*)((char*)As + rs*128 + ((sl ^ (rs & 7)) << 4)) = va;
            const uint4 vb = *(const uint4*)&BT[(size_t)(bn + rs) * K + k0 + sl*8];
            *(uint4*)((char*)Bs + rs*128 + ((sl ^ (rs & 7)) << 4)) = vb;
        }
        __syncthreads();
        #pragma unroll
        for (int kk = 0; kk < 2; ++kk) {
            short8v af[2], bfv[2];
            #pragma unroll
            for (int mf = 0; mf < 2; ++mf) {
                const int row = wm + mf*16 + (lane & 15);
                const int slot = (kk*4 + (lane >> 4)) ^ (row & 7);
                af[mf] = *(const short8v*)((const char*)As + row*128 + (slot << 4));
            }
            #pragma unroll
            for (int nf = 0; nf < 2; ++nf) {
                const int row = wn + nf*16 + (lane & 15);
                const int slot = (kk*4 + (lane >> 4)) ^ (row & 7);
                bfv[nf] = *(const short8v*)((const char*)Bs + row*128 + (slot << 4));
            }
            #pragma unroll
            for (int mf = 0; mf < 2; ++mf)
                #pragma unroll
                for (int nf = 0; nf < 2; ++nf)
                    acc[mf][nf] = __builtin_amdgcn_mfma_f32_16x16x32_bf16(af[mf], bfv[nf], acc[mf][nf], 0, 0, 0);
        }
        __syncthreads();
    }
    #pragma unroll
    for (int nf = 0; nf < 2; ++nf) {
        const int col = bn + wn + nf*16 + (lane & 15);
        const float bv = bias[col];
        const float qs = (SCALEQ && col < D_) ? 0.125f : 1.0f;
        #pragma unroll
        for (int mf = 0; mf < 2; ++mf) {
            #pragma unroll
            for (int r = 0; r < 4; ++r) {
                const int row = bm + wm + mf*16 + (lane >> 4)*4 + r;
                float v = acc[mf][nf][r] + bv;
                if (RELU) v = fmaxf(v, 0.f);
                if (SCALEQ) v *= qs;
                if (OBF16) ((ushort*)Cv)[(size_t)row * N + col] = f2bf(v);
                else       ((float*)Cv)[(size_t)row * N + col] = v;
            }
        }
    }
}

template<int RELU, int OBF16, int SCALEQ>
__global__ __launch_bounds__(256) void mgemm_kernel(const ushort* __restrict__ A,
                                                    const ushort* __restrict__ BT,
                                                    const float* __restrict__ bias,
                                                    void* __restrict__ Cv,
                                                    int M, int N, int K) {
    __shared__ __align__(16) ushort As[64 * 64];
    __shared__ __align__(16) ushort Bs[64 * 64];
    mgemm_body<RELU, OBF16, SCALEQ>(As, Bs, A, BT, bias, Cv, N, K,
                                    blockIdx.y * 64, blockIdx.x * 64);
}

// ---------------------------------------------------------------------------
// relmlp body: both layers MFMA, in-register handoff (w2 k-permuted).
// R11 configuration: 4 pair-tiles (64 pairs) per wave — VGPR 44, below the
// 64-VGPR occupancy cliff (R12's 8-tile variant at 72 VGPR halved occupancy).
// ---------------------------------------------------------------------------
__device__ __forceinline__ void relmlp_body(ushort* w1t, ushort* w2t,
                                            const float* __restrict__ rel,
                                            const float* __restrict__ w1,
                                            const float* __restrict__ b1,
                                            const float* __restrict__ w2,
                                            const float* __restrict__ maskf,
                                            ushort* __restrict__ relbM,
                                            int bid) {
    const int tid = threadIdx.x;
    #pragma unroll
    for (int u = 0; u < 2; ++u) {
        const int n = tid + u*256;
        uint4 o;
        o.x = (unsigned)f2bf(w1[n])        | ((unsigned)f2bf(w1[512 + n])  << 16);
        o.y = (unsigned)f2bf(w1[1024 + n]) | ((unsigned)f2bf(w1[1536 + n]) << 16);
        o.z = (unsigned)f2bf(b1[n]);
        o.w = 0;
        *(uint4*)&w1t[n * 8] = o;
        const int ch = n >> 5, w = n & 31, t = w >> 4, i = w & 15;
        const int s = ((i >> 2) << 3) + (t << 2) + (i & 3);
        const int kpos = ch * 32 + s;
        const float4 wlo = *(const float4*)&w2[n*8];
        const float4 whi = *(const float4*)&w2[n*8 + 4];
        const float wvv[8] = {wlo.x, wlo.y, wlo.z, wlo.w, whi.x, whi.y, whi.z, whi.w};
        #pragma unroll
        for (int h = 0; h < 8; ++h) {
            *(ushort*)((char*)w2t + h*1024 + (((kpos >> 3) ^ h) << 4) + (kpos & 7)*2) = f2bf(wvv[h]);
        }
    }
    __syncthreads();

    const int lane = tid & 63, wvid = tid >> 6;
    const int g = lane >> 4, lr = lane & 15;
    const f32x4 z4 = {0.f, 0.f, 0.f, 0.f};
    const int pbase = bid * 256 + wvid * 64;   // 64 pairs per wave

    short8v rf[4];
    #pragma unroll
    for (int pt = 0; pt < 4; ++pt) {
        short8v r8 = {0,0,0,0,0,0,0,0};
        if (g == 0) {
            const float4 ra = *(const float4*)&rel[(size_t)(pbase + pt*16 + lr) * 4];
            r8[0] = (short)f2bf(ra.x); r8[1] = (short)f2bf(ra.y);
            r8[2] = (short)f2bf(ra.z); r8[3] = (short)f2bf(ra.w);
            r8[4] = (short)0x3F80;
        }
        rf[pt] = r8;
    }
    f32x4 acc[4];
    #pragma unroll
    for (int pt = 0; pt < 4; ++pt) acc[pt] = z4;

    #pragma unroll 2
    for (int ch = 0; ch < 16; ++ch) {
        const short8v a2  = *(const short8v*)((const char*)w2t + (lr & 7)*1024 + (((ch*4 + g) ^ (lr & 7)) << 4));
        const short8v af0 = *(const short8v*)&w1t[(ch*32 + lr) * 8];
        const short8v af1 = *(const short8v*)&w1t[(ch*32 + 16 + lr) * 8];
        #pragma unroll
        for (int pt = 0; pt < 4; ++pt) {
            const f32x4 c0 = __builtin_amdgcn_mfma_f32_16x16x32_bf16(af0, rf[pt], z4, 0, 0, 0);
            const f32x4 c1 = __builtin_amdgcn_mfma_f32_16x16x32_bf16(af1, rf[pt], z4, 0, 0, 0);
            V8 bfrag;
            bfrag.u.x = pk2r(c0[0], c0[1]); bfrag.u.y = pk2r(c0[2], c0[3]);
            bfrag.u.z = pk2r(c1[0], c1[1]); bfrag.u.w = pk2r(c1[2], c1[3]);
            acc[pt] = __builtin_amdgcn_mfma_f32_16x16x32_bf16(a2, bfrag.s, acc[pt], 0, 0, 0);
        }
    }
    if (g < 2) {
        #pragma unroll
        for (int pt = 0; pt < 4; ++pt) {
            const int pair = pbase + pt*16 + lr;
            const int bb_  = pair >> 18;
            const int ij   = pair & 262143;
            const float mv = maskf[bb_ * A_ + (pair & 511)];
            ushort* dst = relbM + (((size_t)(bb_ * 8)) << 18) + ij;
            #pragma unroll
            for (int r = 0; r < 4; ++r) {
                const int h = g*4 + r;
                dst[(size_t)h << 18] = f2bf(16.0f / (1.0f + __expf(-acc[pt][r])) + mv);
            }
        }
    }
}

// ---------------------------------------------------------------------------
// fused: blocks [0,384) qkv GEMM (Q pre-scaled, bf16 out); [384,2432) relmlp.
// ---------------------------------------------------------------------------
__global__ __launch_bounds__(256) void fused_qr_kernel(const ushort* __restrict__ xb,
                                                       const ushort* __restrict__ wtb1,
                                                       const float* __restrict__ qkv_b,
                                                       ushort* __restrict__ qkvb,
                                                       const float* __restrict__ rel,
                                                       const float* __restrict__ w1,
                                                       const float* __restrict__ b1,
                                                       const float* __restrict__ w2,
                                                       const float* __restrict__ maskf,
                                                       ushort* __restrict__ relbM) {
    __shared__ __align__(16) char smem[16384];
    const int bid = blockIdx.x;
    if (bid < 384) {
        mgemm_body<0, 1, 1>((ushort*)smem, (ushort*)(smem + 8192),
                            xb, wtb1, qkv_b, qkvb, 1536, 512,
                            (bid / 24) * 64, (bid % 24) * 64);
    } else {
        relmlp_body((ushort*)smem, (ushort*)(smem + 8192),
                    rel, w1, b1, w2, maskf, relbM, bid - 384);
    }
}

// ---------------------------------------------------------------------------
// VT[bh][d][j] bf16 <- V rows in qkvb. 64x64 tiles.
// ---------------------------------------------------------------------------
__global__ __launch_bounds__(256) void vt_kernel(const ushort* __restrict__ qkvb,
                                                 ushort* __restrict__ VT) {
    const int bh = blockIdx.y, jt = blockIdx.x;
    const int b = bh >> 3, h = bh & 7;
    __shared__ ushort ts[64][72];
    const int tid = threadIdx.x;
    const int r = tid >> 2, c16 = (tid & 3) * 16;
    const ushort* src = qkvb + (size_t)(b*A_ + jt*64 + r) * TD_ + 2*D_ + h*HD_ + c16;
    *(uint4*)&ts[r][c16]     = *(const uint4*)&src[0];
    *(uint4*)&ts[r][c16 + 8] = *(const uint4*)&src[8];
    __syncthreads();
    const int d = tid >> 2, jb = (tid & 3) * 16;
    unsigned pk[8];
    #pragma unroll
    for (int i = 0; i < 8; ++i)
        pk[i] = (unsigned)ts[jb + i*2][d] | ((unsigned)ts[jb + i*2 + 1][d] << 16);
    uint4* dst = (uint4*)&VT[(size_t)(bh*64 + d) * A_ + jt*64 + jb];
    dst[0] = make_uint4(pk[0], pk[1], pk[2], pk[3]);
    dst[1] = make_uint4(pk[4], pk[5], pk[6], pk[7]);
}

// ---------------------------------------------------------------------------
// Fused attention: one wave per (bh, 16-row i-tile). Swapped QK^T; softmax
// in-register; P via swizzled LDS; V-frags straight from VT. S,P never global.
// ---------------------------------------------------------------------------
__global__ __launch_bounds__(64) void attn_kernel(const ushort* __restrict__ qkvb,
                                                  const ushort* __restrict__ relbM,
                                                  const ushort* __restrict__ vtb,
                                                  float* __restrict__ outb) {
    const int blk = blockIdx.x;
    const int bh = blk >> 5, it = blk & 31;
    const int b = bh >> 3, h = bh & 7;
    const int i0 = it * 16;
    const int lane = threadIdx.x;
    const int g = lane >> 4, lr = lane & 15;
    __shared__ __align__(16) ushort Pl[16 * 512];

    const ushort* Qrow = qkvb + (size_t)(b*A_ + i0 + lr) * TD_ + h*HD_;
    const short8v qf0 = *(const short8v*)&Qrow[g*8];
    const short8v qf1 = *(const short8v*)&Qrow[32 + g*8];

    const ushort* Kbase = qkvb + (size_t)(b*A_) * TD_ + D_ + h*HD_;
    f32x4 s[32];
    #pragma unroll
    for (int jt = 0; jt < 32; ++jt) {
        const ushort* Krow = Kbase + (size_t)(jt*16 + lr) * TD_;
        const short8v a0 = *(const short8v*)&Krow[g*8];
        const short8v a1 = *(const short8v*)&Krow[32 + g*8];
        f32x4 c = {0.f, 0.f, 0.f, 0.f};
        c = __builtin_amdgcn_mfma_f32_16x16x32_bf16(a0, qf0, c, 0, 0, 0);
        c = __builtin_amdgcn_mfma_f32_16x16x32_bf16(a1, qf1, c, 0, 0, 0);
        s[jt] = c;
    }
    const ushort* rb = relbM + ((size_t)bh << 18) + (size_t)(i0 + lr) * A_;
    #pragma unroll
    for (int jt = 0; jt < 32; ++jt) {
        const uint2 m2 = *(const uint2*)&rb[jt*16 + g*4];
        s[jt][0] += __uint_as_float(m2.x << 16);
        s[jt][1] += __uint_as_float(m2.x & 0xFFFF0000u);
        s[jt][2] += __uint_as_float(m2.y << 16);
        s[jt][3] += __uint_as_float(m2.y & 0xFFFF0000u);
    }
    float mx = -3.0e38f;
    #pragma unroll
    for (int jt = 0; jt < 32; ++jt)
        mx = fmaxf(mx, fmaxf(fmaxf(s[jt][0], s[jt][1]), fmaxf(s[jt][2], s[jt][3])));
    mx = fmaxf(mx, __shfl_xor(mx, 16));
    mx = fmaxf(mx, __shfl_xor(mx, 32));
    float sum = 0.f;
    #pragma unroll
    for (int jt = 0; jt < 32; ++jt) {
        #pragma unroll
        for (int r = 0; r < 4; ++r) {
            const float e = __expf(s[jt][r] - mx);
            s[jt][r] = e;
            sum += e;
        }
    }
    sum += __shfl_xor(sum, 16);
    sum += __shfl_xor(sum, 32);
    const float inv = 1.0f / sum;
    char* Plc = (char*)Pl;
    #pragma unroll
    for (int jt = 0; jt < 32; ++jt) {
        uint2 w;
        w.x = pk2(s[jt][0] * inv, s[jt][1] * inv);
        w.y = pk2(s[jt][2] * inv, s[jt][3] * inv);
        const int j0 = jt*16 + g*4;
        *(uint2*)(Plc + lr*1024 + (((j0 >> 3) ^ (lr & 7)) << 4) + (j0 & 7)*2) = w;
    }
    __syncthreads();
    f32x4 o[4];
    #pragma unroll
    for (int dt = 0; dt < 4; ++dt) o[dt] = (f32x4){0.f, 0.f, 0.f, 0.f};
    const ushort* Vb = vtb + (size_t)bh * 64 * A_;
    #pragma unroll
    for (int c = 0; c < 16; ++c) {
        const short8v pa = *(const short8v*)(Plc + lr*1024 + (((c*4 + g) ^ (lr & 7)) << 4));
        #pragma unroll
        for (int dt = 0; dt < 4; ++dt) {
            const short8v vf = *(const short8v*)&Vb[(size_t)(dt*16 + lr) * A_ + c*32 + g*8];
            o[dt] = __builtin_amdgcn_mfma_f32_16x16x32_bf16(pa, vf, o[dt], 0, 0, 0);
        }
    }
    float* Ob = outb + (size_t)(b*A_ + i0) * D_ + h*HD_;
    #pragma unroll
    for (int dt = 0; dt < 4; ++dt)
        #pragma unroll
        for (int r = 0; r < 4; ++r)
            Ob[(size_t)(g*4 + r) * D_ + dt*16 + lr] = o[dt][r];
}

// ---------------------------------------------------------------------------
// Fused residual + LayerNorm (512). Optional bf16 copy of the output.
// ---------------------------------------------------------------------------
template<int BF16OUT>
__global__ __launch_bounds__(256) void ln_kernel(const float* __restrict__ a,
                                                 const float* __restrict__ r,
                                                 const float* __restrict__ g,
                                                 const float* __restrict__ bb,
                                                 float* __restrict__ out,
                                                 ushort* __restrict__ outb) {
    const int row = blockIdx.x;
    const int tid = threadIdx.x;
    const size_t base = (size_t)row * D_ + tid * 2;
    const float2 a2 = *reinterpret_cast<const float2*>(&a[base]);
    const float2 r2 = *reinterpret_cast<const float2*>(&r[base]);
    const float e0 = a2.x + r2.x, e1 = a2.y + r2.y;
    float s = e0 + e1;
    float q = e0*e0 + e1*e1;
    #pragma unroll
    for (int o = 32; o > 0; o >>= 1) { s += __shfl_down(s, o); q += __shfl_down(q, o); }
    __shared__ float rs[4], rq[4];
    if ((tid & 63) == 0) { rs[tid >> 6] = s; rq[tid >> 6] = q; }
    __syncthreads();
    const float S = rs[0]+rs[1]+rs[2]+rs[3];
    const float Q = rq[0]+rq[1]+rq[2]+rq[3];
    const float mean = S * (1.0f/512.0f);
    const float var  = Q * (1.0f/512.0f) - mean*mean;
    const float rstd = rsqrtf(var + 1e-5f);
    const int c = tid*2;
    float2 ov;
    ov.x = (e0 - mean)*rstd*g[c]   + bb[c];
    ov.y = (e1 - mean)*rstd*g[c+1] + bb[c+1];
    *reinterpret_cast<float2*>(&out[base]) = ov;
    if (BF16OUT) {
        *(unsigned*)&outb[base] = pk2(ov.x, ov.y);
    }
}

// ---------------------------------------------------------------------------
extern "C" void kernel_launch(void* const* d_in, const int* in_sizes, int n_in,
                              void* d_out, int out_size, void* d_ws, size_t ws_size,
                              hipStream_t stream) {
    const float* x        = (const float*)d_in[0];
    const void*  mask     = d_in[1];
    const float* relation = (const float*)d_in[2];
    const float* qkv_w    = (const float*)d_in[3];
    const float* qkv_b    = (const float*)d_in[4];
    const float* rel_w1   = (const float*)d_in[5];
    const float* rel_b1   = (const float*)d_in[6];
    const float* rel_w2   = (const float*)d_in[7];
    const float* ff_w1    = (const float*)d_in[8];
    const float* ff_b1    = (const float*)d_in[9];
    const float* ff_w2    = (const float*)d_in[10];
    const float* ff_b2    = (const float*)d_in[11];
    const float* ln1_g    = (const float*)d_in[12];
    const float* ln1_b    = (const float*)d_in[13];
    const float* ln2_g    = (const float*)d_in[14];
    const float* ln2_b    = (const float*)d_in[15];
    float* out = (float*)d_out;

    float* ws     = (float*)d_ws;
    ushort* relbM = (ushort*)ws;                   // 4,194,304 ush (bf16, +mask)
    float*  maskf = (float*)(relbM + 4194304);     // 1,024 f
    float*  attnb = maskf + 1024;                  // 524,288 f
    float*  x1    = attnb + 524288;                // 524,288 f
    ushort* wtb1  = (ushort*)(x1 + 524288);        // 786,432 ush (qkv_w^T)
    ushort* wtb2  = wtb1 + 786432;                 // 786,432 ush (ff_w1^T)
    ushort* wtb3  = wtb2 + 786432;                 // 786,432 ush (ff_w2^T)
    ushort* xb    = wtb3 + 786432;                 // 524,288 ush
    ushort* ffhb  = xb  + 524288;                  // 1,572,864 ush
    ushort* qkvb  = ffhb + 1572864;                // 1,572,864 ush (bf16 qkv, Q pre-scaled)
    ushort* vtb   = qkvb + 1572864;                // 524,288 ush (V^T)
    float*  ff2o  = (float*)qkvb;                  // reuse: qkvb dead after attn
    ushort* x1b   = xb;                            // reuse: xb dead after fused_qr

    prep2_kernel<<<833, 256, 0, stream>>>(x, mask, qkv_w, ff_w1, ff_w2,
                                          xb, maskf, wtb1, wtb2, wtb3);
    // qkv GEMM (blocks 0..383) concurrent with relmlp (blocks 384..2431)
    fused_qr_kernel<<<2432, 256, 0, stream>>>(xb, wtb1, qkv_b, qkvb,
                                              relation, rel_w1, rel_b1, rel_w2,
                                              maskf, relbM);
    vt_kernel<<<dim3(8, 16), 256, 0, stream>>>(qkvb, vtb);
    attn_kernel<<<512, 64, 0, stream>>>(qkvb, relbM, vtb, attnb);
    ln_kernel<1><<<1024, 256, 0, stream>>>(attnb, x, ln1_g, ln1_b, x1, x1b);
    mgemm_kernel<1,1,0><<<dim3(24, 16), 256, 0, stream>>>(x1b, wtb2, ff_b1, ffhb, 1024, 1536, 512);
    mgemm_kernel<0,0,0><<<dim3(8, 16), 256, 0, stream>>>(ffhb, wtb3, ff_b2, ff2o, 1024, 512, 1536);
    ln_kernel<0><<<1024, 256, 0, stream>>>(ff2o, x1, ln2_g, ln2_b, out, nullptr);
}

// Round 14
// 96.554 us; speedup vs baseline: 1.0964x; 1.0748x over previous
//
#include <hip/hip_runtime.h>
#include <hip/hip_bf16.h>

#define A_  512
#define D_  512
#define H_  8
#define HD_ 64
#define TD_ 1536   // 3*D
#define RH_ 512    // REL_HID

typedef __attribute__((ext_vector_type(8))) short short8v;
typedef __attribute__((ext_vector_type(4))) float f32x4;
typedef __attribute__((ext_vector_type(4))) unsigned int u32x4;
union V8 { u32x4 u; short8v s; };

__device__ __forceinline__ unsigned short f2bf(float f) {
    unsigned int u = __float_as_uint(f);
    u += 0x7FFFu + ((u >> 16) & 1u);
    return (unsigned short)(u >> 16);
}
// pack 2 f32 -> 2 bf16 in one v_cvt_pk_bf16_f32 (no builtin on gfx950)
__device__ __forceinline__ unsigned pk2(float a, float b) {
    unsigned r;
    asm("v_cvt_pk_bf16_f32 %0, %1, %2" : "=v"(r) : "v"(a), "v"(b));
    return r;
}
// relu + pack
__device__ __forceinline__ unsigned pk2r(float a, float b) {
    return pk2(fmaxf(a, 0.f), fmaxf(b, 0.f));
}

// ---------------------------------------------------------------------------
// Transpose + cvt body: fp32 [R][C] -> bf16 [C][R], 64x64 tile.
// ---------------------------------------------------------------------------
__device__ __forceinline__ void wt_body(float (*ts)[65],
                                        const float* __restrict__ in,
                                        ushort* __restrict__ out,
                                        int R, int C, int bx, int by) {
    const int tid = threadIdx.x;
    const int r0 = by * 64, c0 = bx * 64;
    const int r = tid >> 2, cb = (tid & 3) * 16;
    #pragma unroll
    for (int u = 0; u < 4; ++u) {
        const float4 v = *(const float4*)&in[(size_t)(r0 + r) * C + c0 + cb + u*4];
        ts[r][cb + u*4 + 0] = v.x;
        ts[r][cb + u*4 + 1] = v.y;
        ts[r][cb + u*4 + 2] = v.z;
        ts[r][cb + u*4 + 3] = v.w;
    }
    __syncthreads();
    const int oc = tid & 63;
    const int rb = (tid >> 6) * 16;
    unsigned pk[8];
    #pragma unroll
    for (int i = 0; i < 8; ++i) {
        pk[i] = pk2(ts[rb + i*2][oc], ts[rb + i*2 + 1][oc]);
    }
    uint4* dst = (uint4*)&out[(size_t)(c0 + oc) * R + r0 + rb];
    dst[0] = make_uint4(pk[0], pk[1], pk[2], pk[3]);
    dst[1] = make_uint4(pk[4], pk[5], pk[6], pk[7]);
}

// ---------------------------------------------------------------------------
// prep2: [0,256) x->bf16 ; 256 mask bias ; [257,449) qkv_w^T ;
//        [449,641) ff_w1^T ; [641,833) ff_w2^T.
// ---------------------------------------------------------------------------
__global__ __launch_bounds__(256) void prep2_kernel(const float* __restrict__ x,
                                                    const void* __restrict__ mraw,
                                                    const float* __restrict__ qkv_w,
                                                    const float* __restrict__ ff_w1,
                                                    const float* __restrict__ ff_w2,
                                                    ushort* __restrict__ xb,
                                                    float* __restrict__ maskf,
                                                    ushort* __restrict__ wtb1,
                                                    ushort* __restrict__ wtb2,
                                                    ushort* __restrict__ wtb3) {
    __shared__ __align__(16) float ts[64][65];
    const int tid = threadIdx.x;
    const int bid = blockIdx.x;
    if (bid < 256) {
        const int i = (bid * 256 + tid) * 8;
        const float4 a = *(const float4*)&x[i];
        const float4 b = *(const float4*)&x[i + 4];
        uint4 o;
        o.x = pk2(a.x, a.y);
        o.y = pk2(a.z, a.w);
        o.z = pk2(b.x, b.y);
        o.w = pk2(b.z, b.w);
        *(uint4*)&xb[i] = o;
    } else if (bid == 256) {
        int* anyOdd = (int*)ts;
        if (tid == 0) *anyOdd = 0;
        __syncthreads();
        const unsigned char* mb = (const unsigned char*)mraw;
        int local = 0;
        #pragma unroll
        for (int u = 0; u < 4; ++u) {
            const int i = tid * 4 + u;
            if ((i & 3) != 0 && mb[i] != 0) local = 1;
        }
        if (local) atomicOr(anyOdd, 1);
        __syncthreads();
        const bool isByte = (*anyOdd != 0);
        #pragma unroll
        for (int u = 0; u < 4; ++u) {
            const int i = tid * 4 + u;
            int set = isByte ? (mb[i] != 0) : (((const int*)mraw)[i] != 0);
            maskf[i] = set ? -1e9f : 0.0f;
        }
    } else if (bid < 449) {
        const int i = bid - 257;
        wt_body(ts, qkv_w, wtb1, 512, 1536, i % 24, i / 24);
    } else if (bid < 641) {
        const int i = bid - 449;
        wt_body(ts, ff_w1, wtb2, 512, 1536, i % 24, i / 24);
    } else {
        const int i = bid - 641;
        wt_body(ts, ff_w2, wtb3, 1536, 512, i % 8, i / 8);
    }
}

// ---------------------------------------------------------------------------
// bf16 MFMA GEMM body (64x64 tile, BK=64, 4 waves, slot-XOR swizzle).
// LDAB = row stride of A/BT; KEXT = K extent to accumulate (for split-K).
// ---------------------------------------------------------------------------
template<int RELU, int OBF16, int SCALEQ, int ADDBIAS>
__device__ __forceinline__ void mgemm_body(ushort* As, ushort* Bs,
                                           const ushort* __restrict__ A,
                                           const ushort* __restrict__ BT,
                                           const float* __restrict__ bias,
                                           void* __restrict__ Cv,
                                           int N, int LDAB, int KEXT,
                                           int bm, int bn) {
    const int tid = threadIdx.x;
    const int lane = tid & 63, wave = tid >> 6;
    const int wm = (wave >> 1) * 32, wn = (wave & 1) * 32;
    f32x4 acc[2][2];
    #pragma unroll
    for (int i = 0; i < 2; ++i)
        #pragma unroll
        for (int j = 0; j < 2; ++j) acc[i][j] = (f32x4){0.f, 0.f, 0.f, 0.f};

    const int s0  = tid * 2;
    const int rs  = s0 >> 3;
    const int sl0 = s0 & 7;
    for (int k0 = 0; k0 < KEXT; k0 += 64) {
        #pragma unroll
        for (int u = 0; u < 2; ++u) {
            const int sl = sl0 + u;
            const uint4 va = *(const uint4*)&A[(size_t)(bm + rs) * LDAB + k0 + sl*8];
            *(uint4*)((char*)As + rs*128 + ((sl ^ (rs & 7)) << 4)) = va;
            const uint4 vb = *(const uint4*)&BT[(size_t)(bn + rs) * LDAB + k0 + sl*8];
            *(uint4*)((char*)Bs + rs*128 + ((sl ^ (rs & 7)) << 4)) = vb;
        }
        __syncthreads();
        #pragma unroll
        for (int kk = 0; kk < 2; ++kk) {
            short8v af[2], bfv[2];
            #pragma unroll
            for (int mf = 0; mf < 2; ++mf) {
                const int row = wm + mf*16 + (lane & 15);
                const int slot = (kk*4 + (lane >> 4)) ^ (row & 7);
                af[mf] = *(const short8v*)((const char*)As + row*128 + (slot << 4));
            }
            #pragma unroll
            for (int nf = 0; nf < 2; ++nf) {
                const int row = wn + nf*16 + (lane & 15);
                const int slot = (kk*4 + (lane >> 4)) ^ (row & 7);
                bfv[nf] = *(const short8v*)((const char*)Bs + row*128 + (slot << 4));
            }
            #pragma unroll
            for (int mf = 0; mf < 2; ++mf)
                #pragma unroll
                for (int nf = 0; nf < 2; ++nf)
                    acc[mf][nf] = __builtin_amdgcn_mfma_f32_16x16x32_bf16(af[mf], bfv[nf], acc[mf][nf], 0, 0, 0);
        }
        __syncthreads();
    }
    #pragma unroll
    for (int nf = 0; nf < 2; ++nf) {
        const int col = bn + wn + nf*16 + (lane & 15);
        const float bv = ADDBIAS ? bias[col] : 0.0f;
        const float qs = (SCALEQ && col < D_) ? 0.125f : 1.0f;
        #pragma unroll
        for (int mf = 0; mf < 2; ++mf) {
            #pragma unroll
            for (int r = 0; r < 4; ++r) {
                const int row = bm + wm + mf*16 + (lane >> 4)*4 + r;
                float v = acc[mf][nf][r] + bv;
                if (RELU) v = fmaxf(v, 0.f);
                if (SCALEQ) v *= qs;
                if (OBF16) ((ushort*)Cv)[(size_t)row * N + col] = f2bf(v);
                else       ((float*)Cv)[(size_t)row * N + col] = v;
            }
        }
    }
}

template<int RELU, int OBF16, int SCALEQ>
__global__ __launch_bounds__(256) void mgemm_kernel(const ushort* __restrict__ A,
                                                    const ushort* __restrict__ BT,
                                                    const float* __restrict__ bias,
                                                    void* __restrict__ Cv,
                                                    int M, int N, int K) {
    __shared__ __align__(16) ushort As[64 * 64];
    __shared__ __align__(16) ushort Bs[64 * 64];
    mgemm_body<RELU, OBF16, SCALEQ, 1>(As, Bs, A, BT, bias, Cv, N, K, K,
                                       blockIdx.y * 64, blockIdx.x * 64);
}

// ff2 split-K=2: z selects K-half [z*768,(z+1)*768) and partial buffer.
// Bias is NOT added here (folded into ln2s).
__global__ __launch_bounds__(256) void ff2s_kernel(const ushort* __restrict__ A,
                                                   const ushort* __restrict__ BT,
                                                   float* __restrict__ P0,
                                                   float* __restrict__ P1) {
    __shared__ __align__(16) ushort As[64 * 64];
    __shared__ __align__(16) ushort Bs[64 * 64];
    const int z = blockIdx.z;
    float* P = z ? P1 : P0;
    mgemm_body<0, 0, 0, 0>(As, Bs, A + z*768, BT + z*768, nullptr, P,
                           512, 1536, 768, blockIdx.y * 64, blockIdx.x * 64);
}

// ---------------------------------------------------------------------------
// relmlp body: both layers MFMA, in-register handoff (w2 k-permuted).
// 4 pair-tiles (64 pairs) per wave — VGPR 44, below the 64-VGPR cliff.
// ---------------------------------------------------------------------------
__device__ __forceinline__ void relmlp_body(ushort* w1t, ushort* w2t,
                                            const float* __restrict__ rel,
                                            const float* __restrict__ w1,
                                            const float* __restrict__ b1,
                                            const float* __restrict__ w2,
                                            const float* __restrict__ maskf,
                                            ushort* __restrict__ relbM,
                                            int bid) {
    const int tid = threadIdx.x;
    #pragma unroll
    for (int u = 0; u < 2; ++u) {
        const int n = tid + u*256;
        uint4 o;
        o.x = (unsigned)f2bf(w1[n])        | ((unsigned)f2bf(w1[512 + n])  << 16);
        o.y = (unsigned)f2bf(w1[1024 + n]) | ((unsigned)f2bf(w1[1536 + n]) << 16);
        o.z = (unsigned)f2bf(b1[n]);
        o.w = 0;
        *(uint4*)&w1t[n * 8] = o;
        const int ch = n >> 5, w = n & 31, t = w >> 4, i = w & 15;
        const int s = ((i >> 2) << 3) + (t << 2) + (i & 3);
        const int kpos = ch * 32 + s;
        const float4 wlo = *(const float4*)&w2[n*8];
        const float4 whi = *(const float4*)&w2[n*8 + 4];
        const float wvv[8] = {wlo.x, wlo.y, wlo.z, wlo.w, whi.x, whi.y, whi.z, whi.w};
        #pragma unroll
        for (int h = 0; h < 8; ++h) {
            *(ushort*)((char*)w2t + h*1024 + (((kpos >> 3) ^ h) << 4) + (kpos & 7)*2) = f2bf(wvv[h]);
        }
    }
    __syncthreads();

    const int lane = tid & 63, wvid = tid >> 6;
    const int g = lane >> 4, lr = lane & 15;
    const f32x4 z4 = {0.f, 0.f, 0.f, 0.f};
    const int pbase = bid * 256 + wvid * 64;   // 64 pairs per wave

    short8v rf[4];
    #pragma unroll
    for (int pt = 0; pt < 4; ++pt) {
        short8v r8 = {0,0,0,0,0,0,0,0};
        if (g == 0) {
            const float4 ra = *(const float4*)&rel[(size_t)(pbase + pt*16 + lr) * 4];
            r8[0] = (short)f2bf(ra.x); r8[1] = (short)f2bf(ra.y);
            r8[2] = (short)f2bf(ra.z); r8[3] = (short)f2bf(ra.w);
            r8[4] = (short)0x3F80;
        }
        rf[pt] = r8;
    }
    f32x4 acc[4];
    #pragma unroll
    for (int pt = 0; pt < 4; ++pt) acc[pt] = z4;

    #pragma unroll 2
    for (int ch = 0; ch < 16; ++ch) {
        const short8v a2  = *(const short8v*)((const char*)w2t + (lr & 7)*1024 + (((ch*4 + g) ^ (lr & 7)) << 4));
        const short8v af0 = *(const short8v*)&w1t[(ch*32 + lr) * 8];
        const short8v af1 = *(const short8v*)&w1t[(ch*32 + 16 + lr) * 8];
        #pragma unroll
        for (int pt = 0; pt < 4; ++pt) {
            const f32x4 c0 = __builtin_amdgcn_mfma_f32_16x16x32_bf16(af0, rf[pt], z4, 0, 0, 0);
            const f32x4 c1 = __builtin_amdgcn_mfma_f32_16x16x32_bf16(af1, rf[pt], z4, 0, 0, 0);
            V8 bfrag;
            bfrag.u.x = pk2r(c0[0], c0[1]); bfrag.u.y = pk2r(c0[2], c0[3]);
            bfrag.u.z = pk2r(c1[0], c1[1]); bfrag.u.w = pk2r(c1[2], c1[3]);
            acc[pt] = __builtin_amdgcn_mfma_f32_16x16x32_bf16(a2, bfrag.s, acc[pt], 0, 0, 0);
        }
    }
    if (g < 2) {
        #pragma unroll
        for (int pt = 0; pt < 4; ++pt) {
            const int pair = pbase + pt*16 + lr;
            const int bb_  = pair >> 18;
            const int ij   = pair & 262143;
            const float mv = maskf[bb_ * A_ + (pair & 511)];
            ushort* dst = relbM + (((size_t)(bb_ * 8)) << 18) + ij;
            #pragma unroll
            for (int r = 0; r < 4; ++r) {
                const int h = g*4 + r;
                dst[(size_t)h << 18] = f2bf(16.0f / (1.0f + __expf(-acc[pt][r])) + mv);
            }
        }
    }
}

// ---------------------------------------------------------------------------
// fused: blocks [0,384) qkv GEMM (Q pre-scaled, bf16 out); [384,2432) relmlp.
// ---------------------------------------------------------------------------
__global__ __launch_bounds__(256) void fused_qr_kernel(const ushort* __restrict__ xb,
                                                       const ushort* __restrict__ wtb1,
                                                       const float* __restrict__ qkv_b,
                                                       ushort* __restrict__ qkvb,
                                                       const float* __restrict__ rel,
                                                       const float* __restrict__ w1,
                                                       const float* __restrict__ b1,
                                                       const float* __restrict__ w2,
                                                       const float* __restrict__ maskf,
                                                       ushort* __restrict__ relbM) {
    __shared__ __align__(16) char smem[16384];
    const int bid = blockIdx.x;
    if (bid < 384) {
        mgemm_body<0, 1, 1, 1>((ushort*)smem, (ushort*)(smem + 8192),
                               xb, wtb1, qkv_b, qkvb, 1536, 512, 512,
                               (bid / 24) * 64, (bid % 24) * 64);
    } else {
        relmlp_body((ushort*)smem, (ushort*)(smem + 8192),
                    rel, w1, b1, w2, maskf, relbM, bid - 384);
    }
}

// ---------------------------------------------------------------------------
// VT[bh][d][j] bf16 <- V rows in qkvb. 64x64 tiles.
// ---------------------------------------------------------------------------
__global__ __launch_bounds__(256) void vt_kernel(const ushort* __restrict__ qkvb,
                                                 ushort* __restrict__ VT) {
    const int bh = blockIdx.y, jt = blockIdx.x;
    const int b = bh >> 3, h = bh & 7;
    __shared__ ushort ts[64][72];
    const int tid = threadIdx.x;
    const int r = tid >> 2, c16 = (tid & 3) * 16;
    const ushort* src = qkvb + (size_t)(b*A_ + jt*64 + r) * TD_ + 2*D_ + h*HD_ + c16;
    *(uint4*)&ts[r][c16]     = *(const uint4*)&src[0];
    *(uint4*)&ts[r][c16 + 8] = *(const uint4*)&src[8];
    __syncthreads();
    const int d = tid >> 2, jb = (tid & 3) * 16;
    unsigned pk[8];
    #pragma unroll
    for (int i = 0; i < 8; ++i)
        pk[i] = (unsigned)ts[jb + i*2][d] | ((unsigned)ts[jb + i*2 + 1][d] << 16);
    uint4* dst = (uint4*)&VT[(size_t)(bh*64 + d) * A_ + jt*64 + jb];
    dst[0] = make_uint4(pk[0], pk[1], pk[2], pk[3]);
    dst[1] = make_uint4(pk[4], pk[5], pk[6], pk[7]);
}

// ---------------------------------------------------------------------------
// Fused attention: one wave per (bh, 16-row i-tile). Swapped QK^T; softmax
// in-register; P via swizzled LDS; V-frags straight from VT. S,P never global.
// ---------------------------------------------------------------------------
__global__ __launch_bounds__(64) void attn_kernel(const ushort* __restrict__ qkvb,
                                                  const ushort* __restrict__ relbM,
                                                  const ushort* __restrict__ vtb,
                                                  float* __restrict__ outb) {
    const int blk = blockIdx.x;
    const int bh = blk >> 5, it = blk & 31;
    const int b = bh >> 3, h = bh & 7;
    const int i0 = it * 16;
    const int lane = threadIdx.x;
    const int g = lane >> 4, lr = lane & 15;
    __shared__ __align__(16) ushort Pl[16 * 512];

    const ushort* Qrow = qkvb + (size_t)(b*A_ + i0 + lr) * TD_ + h*HD_;
    const short8v qf0 = *(const short8v*)&Qrow[g*8];
    const short8v qf1 = *(const short8v*)&Qrow[32 + g*8];

    const ushort* Kbase = qkvb + (size_t)(b*A_) * TD_ + D_ + h*HD_;
    f32x4 s[32];
    #pragma unroll
    for (int jt = 0; jt < 32; ++jt) {
        const ushort* Krow = Kbase + (size_t)(jt*16 + lr) * TD_;
        const short8v a0 = *(const short8v*)&Krow[g*8];
        const short8v a1 = *(const short8v*)&Krow[32 + g*8];
        f32x4 c = {0.f, 0.f, 0.f, 0.f};
        c = __builtin_amdgcn_mfma_f32_16x16x32_bf16(a0, qf0, c, 0, 0, 0);
        c = __builtin_amdgcn_mfma_f32_16x16x32_bf16(a1, qf1, c, 0, 0, 0);
        s[jt] = c;
    }
    const ushort* rb = relbM + ((size_t)bh << 18) + (size_t)(i0 + lr) * A_;
    #pragma unroll
    for (int jt = 0; jt < 32; ++jt) {
        const uint2 m2 = *(const uint2*)&rb[jt*16 + g*4];
        s[jt][0] += __uint_as_float(m2.x << 16);
        s[jt][1] += __uint_as_float(m2.x & 0xFFFF0000u);
        s[jt][2] += __uint_as_float(m2.y << 16);
        s[jt][3] += __uint_as_float(m2.y & 0xFFFF0000u);
    }
    float mx = -3.0e38f;
    #pragma unroll
    for (int jt = 0; jt < 32; ++jt)
        mx = fmaxf(mx, fmaxf(fmaxf(s[jt][0], s[jt][1]), fmaxf(s[jt][2], s[jt][3])));
    mx = fmaxf(mx, __shfl_xor(mx, 16));
    mx = fmaxf(mx, __shfl_xor(mx, 32));
    float sum = 0.f;
    #pragma unroll
    for (int jt = 0; jt < 32; ++jt) {
        #pragma unroll
        for (int r = 0; r < 4; ++r) {
            const float e = __expf(s[jt][r] - mx);
            s[jt][r] = e;
            sum += e;
        }
    }
    sum += __shfl_xor(sum, 16);
    sum += __shfl_xor(sum, 32);
    const float inv = 1.0f / sum;
    char* Plc = (char*)Pl;
    #pragma unroll
    for (int jt = 0; jt < 32; ++jt) {
        uint2 w;
        w.x = pk2(s[jt][0] * inv, s[jt][1] * inv);
        w.y = pk2(s[jt][2] * inv, s[jt][3] * inv);
        const int j0 = jt*16 + g*4;
        *(uint2*)(Plc + lr*1024 + (((j0 >> 3) ^ (lr & 7)) << 4) + (j0 & 7)*2) = w;
    }
    __syncthreads();
    f32x4 o[4];
    #pragma unroll
    for (int dt = 0; dt < 4; ++dt) o[dt] = (f32x4){0.f, 0.f, 0.f, 0.f};
    const ushort* Vb = vtb + (size_t)bh * 64 * A_;
    #pragma unroll
    for (int c = 0; c < 16; ++c) {
        const short8v pa = *(const short8v*)(Plc + lr*1024 + (((c*4 + g) ^ (lr & 7)) << 4));
        #pragma unroll
        for (int dt = 0; dt < 4; ++dt) {
            const short8v vf = *(const short8v*)&Vb[(size_t)(dt*16 + lr) * A_ + c*32 + g*8];
            o[dt] = __builtin_amdgcn_mfma_f32_16x16x32_bf16(pa, vf, o[dt], 0, 0, 0);
        }
    }
    float* Ob = outb + (size_t)(b*A_ + i0) * D_ + h*HD_;
    #pragma unroll
    for (int dt = 0; dt < 4; ++dt)
        #pragma unroll
        for (int r = 0; r < 4; ++r)
            Ob[(size_t)(g*4 + r) * D_ + dt*16 + lr] = o[dt][r];
}

// ---------------------------------------------------------------------------
// Fused residual + LayerNorm (512). Optional bf16 copy of the output.
// ---------------------------------------------------------------------------
template<int BF16OUT>
__global__ __launch_bounds__(256) void ln_kernel(const float* __restrict__ a,
                                                 const float* __restrict__ r,
                                                 const float* __restrict__ g,
                                                 const float* __restrict__ bb,
                                                 float* __restrict__ out,
                                                 ushort* __restrict__ outb) {
    const int row = blockIdx.x;
    const int tid = threadIdx.x;
    const size_t base = (size_t)row * D_ + tid * 2;
    const float2 a2 = *reinterpret_cast<const float2*>(&a[base]);
    const float2 r2 = *reinterpret_cast<const float2*>(&r[base]);
    const float e0 = a2.x + r2.x, e1 = a2.y + r2.y;
    float s = e0 + e1;
    float q = e0*e0 + e1*e1;
    #pragma unroll
    for (int o = 32; o > 0; o >>= 1) { s += __shfl_down(s, o); q += __shfl_down(q, o); }
    __shared__ float rs[4], rq[4];
    if ((tid & 63) == 0) { rs[tid >> 6] = s; rq[tid >> 6] = q; }
    __syncthreads();
    const float S = rs[0]+rs[1]+rs[2]+rs[3];
    const float Q = rq[0]+rq[1]+rq[2]+rq[3];
    const float mean = S * (1.0f/512.0f);
    const float var  = Q * (1.0f/512.0f) - mean*mean;
    const float rstd = rsqrtf(var + 1e-5f);
    const int c = tid*2;
    float2 ov;
    ov.x = (e0 - mean)*rstd*g[c]   + bb[c];
    ov.y = (e1 - mean)*rstd*g[c+1] + bb[c+1];
    *reinterpret_cast<float2*>(&out[base]) = ov;
    if (BF16OUT) {
        *(unsigned*)&outb[base] = pk2(ov.x, ov.y);
    }
}

// ---------------------------------------------------------------------------
// ln2s: LN( p0 + p1 + ff_b2 + residual ) — merges ff2 split-K partials.
// ---------------------------------------------------------------------------
__global__ __launch_bounds__(256) void ln2s_kernel(const float* __restrict__ p0,
                                                   const float* __restrict__ p1,
                                                   const float* __restrict__ fb,
                                                   const float* __restrict__ r,
                                                   const float* __restrict__ g,
                                                   const float* __restrict__ bb,
                                                   float* __restrict__ out) {
    const int row = blockIdx.x;
    const int tid = threadIdx.x;
    const size_t base = (size_t)row * D_ + tid * 2;
    const int c = tid*2;
    const float2 a0 = *reinterpret_cast<const float2*>(&p0[base]);
    const float2 a1 = *reinterpret_cast<const float2*>(&p1[base]);
    const float2 r2 = *reinterpret_cast<const float2*>(&r[base]);
    const float2 f2 = *reinterpret_cast<const float2*>(&fb[c]);
    const float e0 = a0.x + a1.x + f2.x + r2.x;
    const float e1 = a0.y + a1.y + f2.y + r2.y;
    float s = e0 + e1;
    float q = e0*e0 + e1*e1;
    #pragma unroll
    for (int o = 32; o > 0; o >>= 1) { s += __shfl_down(s, o); q += __shfl_down(q, o); }
    __shared__ float rs[4], rq[4];
    if ((tid & 63) == 0) { rs[tid >> 6] = s; rq[tid >> 6] = q; }
    __syncthreads();
    const float S = rs[0]+rs[1]+rs[2]+rs[3];
    const float Q = rq[0]+rq[1]+rq[2]+rq[3];
    const float mean = S * (1.0f/512.0f);
    const float var  = Q * (1.0f/512.0f) - mean*mean;
    const float rstd = rsqrtf(var + 1e-5f);
    float2 ov;
    ov.x = (e0 - mean)*rstd*g[c]   + bb[c];
    ov.y = (e1 - mean)*rstd*g[c+1] + bb[c+1];
    *reinterpret_cast<float2*>(&out[base]) = ov;
}

// ---------------------------------------------------------------------------
extern "C" void kernel_launch(void* const* d_in, const int* in_sizes, int n_in,
                              void* d_out, int out_size, void* d_ws, size_t ws_size,
                              hipStream_t stream) {
    const float* x        = (const float*)d_in[0];
    const void*  mask     = d_in[1];
    const float* relation = (const float*)d_in[2];
    const float* qkv_w    = (const float*)d_in[3];
    const float* qkv_b    = (const float*)d_in[4];
    const float* rel_w1   = (const float*)d_in[5];
    const float* rel_b1   = (const float*)d_in[6];
    const float* rel_w2   = (const float*)d_in[7];
    const float* ff_w1    = (const float*)d_in[8];
    const float* ff_b1    = (const float*)d_in[9];
    const float* ff_w2    = (const float*)d_in[10];
    const float* ff_b2    = (const float*)d_in[11];
    const float* ln1_g    = (const float*)d_in[12];
    const float* ln1_b    = (const float*)d_in[13];
    const float* ln2_g    = (const float*)d_in[14];
    const float* ln2_b    = (const float*)d_in[15];
    float* out = (float*)d_out;

    float* ws     = (float*)d_ws;
    ushort* relbM = (ushort*)ws;                   // 4,194,304 ush (bf16, +mask)
    float*  maskf = (float*)(relbM + 4194304);     // 1,024 f
    float*  attnb = maskf + 1024;                  // 524,288 f
    float*  x1    = attnb + 524288;                // 524,288 f
    ushort* wtb1  = (ushort*)(x1 + 524288);        // 786,432 ush (qkv_w^T)
    ushort* wtb2  = wtb1 + 786432;                 // 786,432 ush (ff_w1^T)
    ushort* wtb3  = wtb2 + 786432;                 // 786,432 ush (ff_w2^T)
    ushort* xb    = wtb3 + 786432;                 // 524,288 ush
    ushort* ffhb  = xb  + 524288;                  // 1,572,864 ush
    ushort* qkvb  = ffhb + 1572864;                // 1,572,864 ush (bf16 qkv, Q pre-scaled)
    ushort* vtb   = qkvb + 1572864;                // 524,288 ush (V^T)
    float*  ff2p0 = (float*)qkvb;                  // 524,288 f (qkvb dead after attn)
    float*  ff2p1 = (float*)relbM;                 // 524,288 f (relbM dead after attn)
    ushort* x1b   = xb;                            // reuse: xb dead after fused_qr

    prep2_kernel<<<833, 256, 0, stream>>>(x, mask, qkv_w, ff_w1, ff_w2,
                                          xb, maskf, wtb1, wtb2, wtb3);
    // qkv GEMM (blocks 0..383) concurrent with relmlp (blocks 384..2431)
    fused_qr_kernel<<<2432, 256, 0, stream>>>(xb, wtb1, qkv_b, qkvb,
                                              relation, rel_w1, rel_b1, rel_w2,
                                              maskf, relbM);
    vt_kernel<<<dim3(8, 16), 256, 0, stream>>>(qkvb, vtb);
    attn_kernel<<<512, 64, 0, stream>>>(qkvb, relbM, vtb, attnb);
    ln_kernel<1><<<1024, 256, 0, stream>>>(attnb, x, ln1_g, ln1_b, x1, x1b);
    mgemm_kernel<1,1,0><<<dim3(24, 16), 256, 0, stream>>>(x1b, wtb2, ff_b1, ffhb, 1024, 1536, 512);
    // ff2 split-K=2: full-device grid (8x16x2 = 256 blocks), bias folded into ln2s
    ff2s_kernel<<<dim3(8, 16, 2), 256, 0, stream>>>(ffhb, wtb3, ff2p0, ff2p1);
    ln2s_kernel<<<1024, 256, 0, stream>>>(ff2p0, ff2p1, ff_b2, x1, ln2_g, ln2_b, out);
}